// Round 1
// baseline (5611.671 us; speedup 1.0000x reference)
//
#include <hip/hip_runtime.h>

#define LRELU_SLOPE 0.01f
#define BN_EPS 1e-5f

constexpr int B_ = 2, T_ = 8, Z_ = 16, Y_ = 32, X_ = 32;
constexpr int SP   = T_ * Z_ * Y_ * X_;   // 131072 spatial per (b,c) plane
constexpr int NPOS = B_ * SP;             // 262144
constexpr int NBLK = NPOS / 256;          // 1024 conv blocks

// ---------------------------------------------------------------- weights
// Repack W[co][ci][kt][kz][ky][kx] -> Wt[ci][k625][co]  (co contiguous,
// index wave-uniform in the conv hot loop -> scalar s_load path)
__global__ void repack_kernel(const float* __restrict__ W, float* __restrict__ Wt,
                              int Cout, int Cin) {
    int i = blockIdx.x * 256 + threadIdx.x;
    int total = Cout * Cin * 625;
    if (i >= total) return;
    int co = i / (Cin * 625);
    int r  = i % (Cin * 625);
    int ci = r / 625;
    int k  = r % 625;
    Wt[(ci * 625 + k) * Cout + co] = W[i];
}

// ---------------------------------------------------------------- embed
// h0[b][c][sp] = sum_f x[b][sp][f] * wemb[f][c] + bemb[c]
__global__ void embed_kernel(const float* __restrict__ x, const float* __restrict__ wemb,
                             const float* __restrict__ bemb, float* __restrict__ out) {
    int g = blockIdx.x * 256 + threadIdx.x;       // 0..NPOS
    const float* xr = x + (size_t)g * 8;
    float xv[8];
#pragma unroll
    for (int f = 0; f < 8; ++f) xv[f] = xr[f];
    int b = g >> 17;           // g / SP
    int sp = g & (SP - 1);
#pragma unroll
    for (int c = 0; c < 16; ++c) {
        float a = bemb[c];
#pragma unroll
        for (int f = 0; f < 8; ++f) a = fmaf(xv[f], wemb[f * 16 + c], a);
        out[((size_t)(b * 16 + c)) * SP + sp] = a;
    }
}

// ---------------------------------------------------------------- conv4d
// One thread per output position, all COUT channels accumulated in VGPRs.
// Weight reads are wave-uniform (scalar pipe). Input reads x-coalesced.
// Epilogue: write conv+bias, block-reduce per-channel sum/sumsq.
template <int CIN, int COUT>
__global__ __launch_bounds__(256) void conv_kernel(
        const float* __restrict__ in, const float* __restrict__ wt,
        const float* __restrict__ bias, float* __restrict__ out,
        float* __restrict__ ps, float* __restrict__ psq) {
    int blk = blockIdx.x;
    int yt = blk & 3, z = (blk >> 2) & 15, t = (blk >> 6) & 7, b = blk >> 9;
    int tid = threadIdx.x;
    int x = tid & 31;
    int y = yt * 8 + (tid >> 5);

    float acc[COUT];
#pragma unroll
    for (int co = 0; co < COUT; ++co) acc[co] = 0.f;

#pragma unroll 1
    for (int ci = 0; ci < CIN; ++ci) {
        const float* inb = in + ((size_t)(b * CIN + ci)) * SP;
#pragma unroll 1
        for (int kt = 0; kt < 5; ++kt) {
            int tt = t + kt - 2;
            if ((unsigned)tt >= (unsigned)T_) continue;   // uniform skip
#pragma unroll 1
            for (int kz = 0; kz < 5; ++kz) {
                int zz = z + kz - 2;
                if ((unsigned)zz >= (unsigned)Z_) continue; // uniform skip
#pragma unroll 1
                for (int ky = 0; ky < 5; ++ky) {
                    int yy = y + ky - 2;
                    bool vy = (unsigned)yy < (unsigned)Y_;
                    const float* rowp = inb + ((size_t)((tt * Z_ + zz) * Y_ + (vy ? yy : 0))) * X_;
                    float v[5];
#pragma unroll
                    for (int kx = 0; kx < 5; ++kx) {
                        int xx = x + kx - 2;
                        bool ok = vy && ((unsigned)xx < (unsigned)X_);
                        v[kx] = ok ? rowp[xx] : 0.f;
                    }
                    const float* wr = wt + (size_t)((ci * 625) + ((kt * 5 + kz) * 5 + ky) * 5) * COUT;
#pragma unroll
                    for (int kx = 0; kx < 5; ++kx) {
#pragma unroll
                        for (int co = 0; co < COUT; ++co)
                            acc[co] = fmaf(v[kx], wr[kx * COUT + co], acc[co]);
                    }
                }
            }
        }
    }

    // ---- epilogue: store conv+bias, per-channel block stats
    __shared__ float lsum[COUT];
    __shared__ float lsq[COUT];
    if (tid < COUT) { lsum[tid] = 0.f; lsq[tid] = 0.f; }
    __syncthreads();

    int sp = ((t * Z_ + z) * Y_ + y) * X_ + x;
    int lane = tid & 63;
#pragma unroll
    for (int co = 0; co < COUT; ++co) {
        float val = acc[co] + bias[co];
        out[((size_t)(b * COUT + co)) * SP + sp] = val;
        float s = val, q = val * val;
#pragma unroll
        for (int off = 32; off >= 1; off >>= 1) {
            s += __shfl_down(s, off, 64);
            q += __shfl_down(q, off, 64);
        }
        if (lane == 0) { atomicAdd(&lsum[co], s); atomicAdd(&lsq[co], q); }
    }
    __syncthreads();
    if (tid < COUT) {
        ps[tid * NBLK + blk]  = lsum[tid];
        psq[tid * NBLK + blk] = lsq[tid];
    }
}

// ---------------------------------------------------------------- bn stats
// grid = COUT blocks; folds mean/var/gamma/beta into per-channel scale/shift
__global__ void stats_kernel(const float* __restrict__ ps, const float* __restrict__ psq,
                             const float* __restrict__ g, const float* __restrict__ beta,
                             float* __restrict__ scale, float* __restrict__ shift) {
    int co = blockIdx.x;
    int tid = threadIdx.x;   // 256
    float s = 0.f, q = 0.f;
    for (int i = tid; i < NBLK; i += 256) {
        s += ps[co * NBLK + i];
        q += psq[co * NBLK + i];
    }
#pragma unroll
    for (int off = 32; off >= 1; off >>= 1) {
        s += __shfl_down(s, off, 64);
        q += __shfl_down(q, off, 64);
    }
    __shared__ float ss[4], qq[4];
    int w = tid >> 6, lane = tid & 63;
    if (lane == 0) { ss[w] = s; qq[w] = q; }
    __syncthreads();
    if (tid == 0) {
        float S = ss[0] + ss[1] + ss[2] + ss[3];
        float Q = qq[0] + qq[1] + qq[2] + qq[3];
        float m = S / (float)NPOS;
        float var = Q / (float)NPOS - m * m;
        float rstd = rsqrtf(var + BN_EPS);
        float sc = g[co] * rstd;
        scale[co] = sc;
        shift[co] = beta[co] - m * sc;
    }
}

// ---------------------------------------------------------------- bn + leaky relu (in-place, float4)
__global__ void bn_lrelu_kernel(float* __restrict__ buf, const float* __restrict__ scale,
                                const float* __restrict__ shift, int C) {
    int i = blockIdx.x * 256 + threadIdx.x;   // float4 index
    int n4 = B_ * C * SP / 4;
    if (i >= n4) return;
    int c = (i >> 15) % C;                    // (4*i / SP) % C
    float sc = scale[c], sh = shift[c];
    float4* p = (float4*)buf;
    float4 v = p[i];
    float a0 = v.x * sc + sh, a1 = v.y * sc + sh, a2 = v.z * sc + sh, a3 = v.w * sc + sh;
    v.x = a0 > 0.f ? a0 : LRELU_SLOPE * a0;
    v.y = a1 > 0.f ? a1 : LRELU_SLOPE * a1;
    v.z = a2 > 0.f ? a2 : LRELU_SLOPE * a2;
    v.w = a3 > 0.f ? a3 : LRELU_SLOPE * a3;
    p[i] = v;
}

// ---------------------------------------------------------------- final projection
__global__ void proj_kernel(const float* __restrict__ h, const float* __restrict__ wp,
                            const float* __restrict__ bp, float* __restrict__ out) {
    int g = blockIdx.x * 256 + threadIdx.x;   // 0..NPOS
    int b = g >> 17;
    int sp = g & (SP - 1);
    const float* hb = h + (size_t)b * 16 * SP + sp;
    float a = bp[0];
#pragma unroll
    for (int c = 0; c < 16; ++c) a = fmaf(hb[(size_t)c * SP], wp[c], a);
    out[g] = a;
}

// ---------------------------------------------------------------- launch
extern "C" void kernel_launch(void* const* d_in, const int* in_sizes, int n_in,
                              void* d_out, int out_size, void* d_ws, size_t ws_size,
                              hipStream_t stream) {
    const float* x    = (const float*)d_in[0];
    const float* wemb = (const float*)d_in[1];
    const float* bemb = (const float*)d_in[2];
    const float* W1   = (const float*)d_in[3];
    const float* b1   = (const float*)d_in[4];
    const float* g1   = (const float*)d_in[5];
    const float* be1  = (const float*)d_in[6];
    const float* W2   = (const float*)d_in[7];
    const float* b2   = (const float*)d_in[8];
    const float* g2   = (const float*)d_in[9];
    const float* be2  = (const float*)d_in[10];
    const float* W3   = (const float*)d_in[11];
    const float* b3   = (const float*)d_in[12];
    const float* g3   = (const float*)d_in[13];
    const float* be3  = (const float*)d_in[14];
    const float* wp   = (const float*)d_in[15];
    const float* bp   = (const float*)d_in[16];

    float* ws = (float*)d_ws;
    float* A    = ws;                       // 32ch buffer: 8,388,608 floats
    float* Bf   = ws + 8388608;             // 32ch buffer: 8,388,608 floats
    float* wt1  = ws + 16777216;            // 160000
    float* wt2  = wt1 + 160000;             // 320000
    float* wt3  = wt2 + 320000;             // 320000
    float* ps   = wt3 + 320000;             // 32*NBLK = 32768
    float* psq  = ps + 32768;               // 32768
    float* scale = psq + 32768;             // 32
    float* shift = scale + 32;              // 32

    repack_kernel<<<(16 * 16 * 625 + 255) / 256, 256, 0, stream>>>(W1, wt1, 16, 16);
    repack_kernel<<<(32 * 16 * 625 + 255) / 256, 256, 0, stream>>>(W2, wt2, 32, 16);
    repack_kernel<<<(16 * 32 * 625 + 255) / 256, 256, 0, stream>>>(W3, wt3, 16, 32);

    embed_kernel<<<NPOS / 256, 256, 0, stream>>>(x, wemb, bemb, A);

    // layer 1: 16 -> 16
    conv_kernel<16, 16><<<NBLK, 256, 0, stream>>>(A, wt1, b1, Bf, ps, psq);
    stats_kernel<<<16, 256, 0, stream>>>(ps, psq, g1, be1, scale, shift);
    bn_lrelu_kernel<<<B_ * 16 * SP / 1024, 256, 0, stream>>>(Bf, scale, shift, 16);

    // layer 2: 16 -> 32
    conv_kernel<16, 32><<<NBLK, 256, 0, stream>>>(Bf, wt2, b2, A, ps, psq);
    stats_kernel<<<32, 256, 0, stream>>>(ps, psq, g2, be2, scale, shift);
    bn_lrelu_kernel<<<B_ * 32 * SP / 1024, 256, 0, stream>>>(A, scale, shift, 32);

    // layer 3: 32 -> 16
    conv_kernel<32, 16><<<NBLK, 256, 0, stream>>>(A, wt3, b3, Bf, ps, psq);
    stats_kernel<<<16, 256, 0, stream>>>(ps, psq, g3, be3, scale, shift);
    bn_lrelu_kernel<<<B_ * 16 * SP / 1024, 256, 0, stream>>>(Bf, scale, shift, 16);

    proj_kernel<<<NPOS / 256, 256, 0, stream>>>(Bf, wp, bp, (float*)d_out);
}

// Round 2
// 1613.029 us; speedup vs baseline: 3.4790x; 3.4790x over previous
//
#include <hip/hip_runtime.h>

#define LRELU_SLOPE 0.01f
#define BN_EPS 1e-5f

constexpr int B_ = 2, T_ = 8, Z_ = 16, Y_ = 32, X_ = 32;
constexpr int SP   = T_ * Z_ * Y_ * X_;   // 131072
constexpr int NPOS = B_ * SP;             // 262144
constexpr int Tp = 12, Zp = 20, Yp = 36, Xp = 36;   // padded dims (+2 each side)
constexpr int NROW = B_ * T_ * Z_ * Y_;   // 8192 x-rows
constexpr int NBLK2 = 2048;               // conv blocks (4 waves each, 1 row/wave)

typedef float v4f  __attribute__((ext_vector_type(4)));
typedef __bf16 v8bf __attribute__((ext_vector_type(8)));
typedef short  v8s  __attribute__((ext_vector_type(8)));

static __device__ __forceinline__ float bf2f(short s) {
    unsigned int u = ((unsigned int)(unsigned short)s) << 16;
    float f; __builtin_memcpy(&f, &u, 4); return f;
}
static __device__ __forceinline__ short f2bf(float f) {
    unsigned int u; __builtin_memcpy(&u, &f, 4);
    u += 0x7FFF + ((u >> 16) & 1);
    return (short)(u >> 16);
}
static __device__ __forceinline__ v4f mfma16(v8bf a, v8bf b, v4f c) {
    return __builtin_amdgcn_mfma_f32_16x16x32_bf16(a, b, c, 0, 0, 0);
}

// ------------------------------------------------------------ weight repack
// W[co][ci][625] fp32  ->  WB[o 626][co][ci] bf16   (o==625 is a zero block
// used as the dummy partner when pairing the odd kx=4 offset)
__global__ void repack_bf16(const float* __restrict__ W, short* __restrict__ WB,
                            int CO, int CI) {
    int i = blockIdx.x * 256 + threadIdx.x;
    int total = 626 * CO * CI;
    if (i >= total) return;
    int o = i / (CO * CI);
    int r = i % (CO * CI);
    int co = r / CI, ci = r % CI;
    WB[i] = (o == 625) ? (short)0 : f2bf(W[(size_t)(co * CI + ci) * 625 + o]);
}

// ------------------------------------------------------------ embed -> padded bf16 channel-last
__global__ void embed_kernel(const float* __restrict__ x, const float* __restrict__ wemb,
                             const float* __restrict__ bemb, short* __restrict__ outp) {
    int g = blockIdx.x * 256 + threadIdx.x;   // position id
    const float* xr = x + (size_t)g * 8;
    float xv[8];
#pragma unroll
    for (int f = 0; f < 8; ++f) xv[f] = xr[f];
    int xx = g & 31, yy = (g >> 5) & 31, zz = (g >> 10) & 15, tt = (g >> 14) & 7, bb = g >> 17;
    size_t addr = ((((size_t)(bb * Tp + tt + 2) * Zp + zz + 2) * Yp + yy + 2) * Xp + xx + 2) * 16;
    short ov[16];
#pragma unroll
    for (int c = 0; c < 16; ++c) {
        float a = bemb[c];
#pragma unroll
        for (int f = 0; f < 8; ++f) a = fmaf(xv[f], wemb[f * 16 + c], a);
        ov[c] = f2bf(a);
    }
    *(v8s*)(outp + addr)     = *(v8s*)ov;
    *(v8s*)(outp + addr + 8) = *(v8s*)(ov + 8);
}

// ------------------------------------------------------------ conv4d via MFMA implicit GEMM
// Wave = one x-row (32 positions = 2 M-tiles). K = Cin*625.
// CI==16: K-pair = (2 kx offsets) x 16ci ; CI==32: K = 32ci per offset.
template <int CI, int CO>
__global__ __launch_bounds__(256) void conv_mfma(
        const short* __restrict__ inp,   // padded bf16 [b][tp][zp][yp][xp][CI]
        const short* __restrict__ wb,    // bf16 [626][CO][CI]
        const float* __restrict__ bias,
        short* __restrict__ outp,        // padded bf16 [b][tp][zp][yp][xp][CO]
        float* __restrict__ ps, float* __restrict__ psq) {
    constexpr int NT = CO / 16;
    const int tid = threadIdx.x;
    const int w = tid >> 6, lane = tid & 63;
    const int row = blockIdx.x * 4 + w;
    const int y = row & 31, z = (row >> 5) & 15, t = (row >> 9) & 7, b = row >> 12;
    const int q = lane >> 4, m = lane & 15;

    int a_offp, cig;
    if (CI == 16) { a_offp = q >> 1; cig = (q & 1) * 8; }
    else          { a_offp = 0;      cig = q * 8; }
    const int lane_a = (m + a_offp) * CI + cig;
    const int lane_b = m * CI + cig;
    const int sel = (CI == 16) ? (q >> 1) : 0;

    v4f acc[2][NT];
#pragma unroll
    for (int mt = 0; mt < 2; ++mt)
#pragma unroll
        for (int nt = 0; nt < NT; ++nt) acc[mt][nt] = (v4f){0.f, 0.f, 0.f, 0.f};

#pragma unroll 1
    for (int kt = 0; kt < 5; ++kt) {
#pragma unroll 1
        for (int kz = 0; kz < 5; ++kz) {
            const size_t tz = ((size_t)((b * Tp + t + kt) * Zp + (z + kz))) * Yp;
#pragma unroll 1
            for (int ky = 0; ky < 5; ++ky) {
                const short* rowp = inp + (tz + (y + ky)) * (Xp * CI);
                const int obase = ((kt * 5 + kz) * 5 + ky) * 5;
                if (CI == 16) {
#pragma unroll
                    for (int kxp = 0; kxp < 3; ++kxp) {
                        const int kx0 = kxp * 2;
                        const int o0 = obase + kx0;
                        const int od = (kxp < 2) ? 1 : (625 - o0);
                        const int oq = o0 + sel * od;
                        const short* ap = rowp + lane_a + kx0 * CI;
                        v8bf A0 = *(const v8bf*)(ap);
                        v8bf A1 = *(const v8bf*)(ap + 16 * CI);
                        const short* bpp = wb + (size_t)oq * (CO * CI) + lane_b;
#pragma unroll
                        for (int nt = 0; nt < NT; ++nt) {
                            v8bf Bf = *(const v8bf*)(bpp + nt * (16 * CI));
                            acc[0][nt] = mfma16(A0, Bf, acc[0][nt]);
                            acc[1][nt] = mfma16(A1, Bf, acc[1][nt]);
                        }
                    }
                } else {
#pragma unroll
                    for (int kx = 0; kx < 5; ++kx) {
                        const int o = obase + kx;
                        const short* ap = rowp + lane_a + kx * CI;
                        v8bf A0 = *(const v8bf*)(ap);
                        v8bf A1 = *(const v8bf*)(ap + 16 * CI);
                        const short* bpp = wb + (size_t)o * (CO * CI) + lane_b;
#pragma unroll
                        for (int nt = 0; nt < NT; ++nt) {
                            v8bf Bf = *(const v8bf*)(bpp + nt * (16 * CI));
                            acc[0][nt] = mfma16(A0, Bf, acc[0][nt]);
                            acc[1][nt] = mfma16(A1, Bf, acc[1][nt]);
                        }
                    }
                }
            }
        }
    }

    // ---- epilogue: bias, bf16 store to padded out, per-channel block stats
    __shared__ float lsum[CO], lsq[CO];
    for (int i = tid; i < CO; i += 256) { lsum[i] = 0.f; lsq[i] = 0.f; }
    __syncthreads();

    const size_t orow = ((((size_t)(b * Tp + t + 2) * Zp + (z + 2)) * Yp + (y + 2)) * Xp + 2) * CO;
#pragma unroll
    for (int mt = 0; mt < 2; ++mt) {
#pragma unroll
        for (int nt = 0; nt < NT; ++nt) {
            const int co = m + nt * 16;
            const float bv = bias[co];
            float s = 0.f, sq = 0.f;
#pragma unroll
            for (int r = 0; r < 4; ++r) {
                float v = acc[mt][nt][r] + bv;
                int xx = mt * 16 + q * 4 + r;
                outp[orow + (size_t)xx * CO + co] = f2bf(v);
                s += v; sq += v * v;
            }
            s += __shfl_down(s, 32, 64);  sq += __shfl_down(sq, 32, 64);
            s += __shfl_down(s, 16, 64);  sq += __shfl_down(sq, 16, 64);
            if (lane < 16) { atomicAdd(&lsum[co], s); atomicAdd(&lsq[co], sq); }
        }
    }
    __syncthreads();
    for (int i = tid; i < CO; i += 256) {
        ps[(size_t)i * NBLK2 + blockIdx.x]  = lsum[i];
        psq[(size_t)i * NBLK2 + blockIdx.x] = lsq[i];
    }
}

// ------------------------------------------------------------ bn stats: fold into scale/shift
__global__ void stats_kernel(const float* __restrict__ ps, const float* __restrict__ psq,
                             const float* __restrict__ g, const float* __restrict__ beta,
                             float* __restrict__ scale, float* __restrict__ shift) {
    int co = blockIdx.x;
    int tid = threadIdx.x;
    float s = 0.f, q = 0.f;
    for (int i = tid; i < NBLK2; i += 256) {
        s += ps[(size_t)co * NBLK2 + i];
        q += psq[(size_t)co * NBLK2 + i];
    }
#pragma unroll
    for (int off = 32; off >= 1; off >>= 1) {
        s += __shfl_down(s, off, 64);
        q += __shfl_down(q, off, 64);
    }
    __shared__ float ss[4], qq[4];
    int w = tid >> 6, lane = tid & 63;
    if (lane == 0) { ss[w] = s; qq[w] = q; }
    __syncthreads();
    if (tid == 0) {
        float S = ss[0] + ss[1] + ss[2] + ss[3];
        float Q = qq[0] + qq[1] + qq[2] + qq[3];
        float mn = S / (float)NPOS;
        float var = Q / (float)NPOS - mn * mn;
        float rstd = rsqrtf(var + BN_EPS);
        float sc = g[co] * rstd;
        scale[co] = sc;
        shift[co] = beta[co] - mn * sc;
    }
}

// ------------------------------------------------------------ bn + leaky relu, in-place on padded bf16
template <int C>
__global__ void bn_lrelu_pad(short* __restrict__ buf, const float* __restrict__ scale,
                             const float* __restrict__ shift) {
    constexpr int GPR = 32 * C / 8;            // 8-elem groups per row
    int gidx = blockIdx.x * 256 + threadIdx.x;
    int row = gidx / GPR;
    int gi = gidx % GPR;
    int xx = gi / (C / 8), c0 = (gi % (C / 8)) * 8;
    int y = row & 31, z = (row >> 5) & 15, t = (row >> 9) & 7, b = row >> 12;
    size_t addr = ((((size_t)(b * Tp + t + 2) * Zp + z + 2) * Yp + y + 2) * Xp + xx + 2) * C + c0;
    v8s v = *(v8s*)(buf + addr);
    short o[8];
#pragma unroll
    for (int j = 0; j < 8; ++j) {
        int c = c0 + j;
        float f = bf2f(v[j]) * scale[c] + shift[c];
        f = f > 0.f ? f : LRELU_SLOPE * f;
        o[j] = f2bf(f);
    }
    *(v8s*)(buf + addr) = *(v8s*)o;
}

// ------------------------------------------------------------ final: bn3 + lrelu + projection
__global__ void bnproj_kernel(const short* __restrict__ h, const float* __restrict__ scale,
                              const float* __restrict__ shift, const float* __restrict__ wp,
                              const float* __restrict__ bp, float* __restrict__ out) {
    int g = blockIdx.x * 256 + threadIdx.x;
    int xx = g & 31, yy = (g >> 5) & 31, zz = (g >> 10) & 15, tt = (g >> 14) & 7, bb = g >> 17;
    size_t addr = ((((size_t)(bb * Tp + tt + 2) * Zp + zz + 2) * Yp + yy + 2) * Xp + xx + 2) * 16;
    v8s lo = *(const v8s*)(h + addr);
    v8s hi = *(const v8s*)(h + addr + 8);
    float a = bp[0];
#pragma unroll
    for (int j = 0; j < 8; ++j) {
        float f = bf2f(lo[j]) * scale[j] + shift[j];
        f = f > 0.f ? f : LRELU_SLOPE * f;
        a = fmaf(f, wp[j], a);
    }
#pragma unroll
    for (int j = 0; j < 8; ++j) {
        float f = bf2f(hi[j]) * scale[8 + j] + shift[8 + j];
        f = f > 0.f ? f : LRELU_SLOPE * f;
        a = fmaf(f, wp[8 + j], a);
    }
    out[g] = a;
}

// ------------------------------------------------------------ launch
extern "C" void kernel_launch(void* const* d_in, const int* in_sizes, int n_in,
                              void* d_out, int out_size, void* d_ws, size_t ws_size,
                              hipStream_t stream) {
    const float* x    = (const float*)d_in[0];
    const float* wemb = (const float*)d_in[1];
    const float* bemb = (const float*)d_in[2];
    const float* W1   = (const float*)d_in[3];
    const float* b1   = (const float*)d_in[4];
    const float* g1   = (const float*)d_in[5];
    const float* be1  = (const float*)d_in[6];
    const float* W2   = (const float*)d_in[7];
    const float* b2   = (const float*)d_in[8];
    const float* g2   = (const float*)d_in[9];
    const float* be2  = (const float*)d_in[10];
    const float* W3   = (const float*)d_in[11];
    const float* b3   = (const float*)d_in[12];
    const float* g3   = (const float*)d_in[13];
    const float* be3  = (const float*)d_in[14];
    const float* wp   = (const float*)d_in[15];
    const float* bp   = (const float*)d_in[16];

    char* base = (char*)d_ws;
    short* P16A = (short*)(base);                  // 19,906,560 B
    short* P16B = (short*)(base + 19906560);       // 19,906,560 B
    short* P32  = (short*)(base + 39813120);       // 39,813,120 B
    short* WB1  = (short*)(base + 79626240);       // 320,512 B
    short* WB2  = (short*)(base + 79946752);       // 641,024 B
    short* WB3  = (short*)(base + 80587776);       // 641,024 B
    float* ps   = (float*)(base + 81228800);       // 262,144 B
    float* psq  = (float*)(base + 81490944);       // 262,144 B
    float* scale= (float*)(base + 81753088);       // 128 B
    float* shift= (float*)(base + 81753216);       // 128 B

    // zero the three padded activation buffers (padding must be 0 every call)
    hipMemsetAsync(base, 0, 79626240, stream);

    repack_bf16<<<(626 * 16 * 16 + 255) / 256, 256, 0, stream>>>(W1, WB1, 16, 16);
    repack_bf16<<<(626 * 32 * 16 + 255) / 256, 256, 0, stream>>>(W2, WB2, 32, 16);
    repack_bf16<<<(626 * 16 * 32 + 255) / 256, 256, 0, stream>>>(W3, WB3, 16, 32);

    embed_kernel<<<NPOS / 256, 256, 0, stream>>>(x, wemb, bemb, P16A);

    // layer 1: 16 -> 16
    conv_mfma<16, 16><<<NBLK2, 256, 0, stream>>>(P16A, WB1, b1, P16B, ps, psq);
    stats_kernel<<<16, 256, 0, stream>>>(ps, psq, g1, be1, scale, shift);
    bn_lrelu_pad<16><<<NROW * 64 / 256, 256, 0, stream>>>(P16B, scale, shift);

    // layer 2: 16 -> 32
    conv_mfma<16, 32><<<NBLK2, 256, 0, stream>>>(P16B, WB2, b2, P32, ps, psq);
    stats_kernel<<<32, 256, 0, stream>>>(ps, psq, g2, be2, scale, shift);
    bn_lrelu_pad<32><<<NROW * 128 / 256, 256, 0, stream>>>(P32, scale, shift);

    // layer 3: 32 -> 16
    conv_mfma<32, 16><<<NBLK2, 256, 0, stream>>>(P32, WB3, b3, P16A, ps, psq);
    stats_kernel<<<16, 256, 0, stream>>>(ps, psq, g3, be3, scale, shift);

    bnproj_kernel<<<NPOS / 256, 256, 0, stream>>>(P16A, scale, shift, wp, bp, (float*)d_out);
}

// Round 3
// 608.018 us; speedup vs baseline: 9.2294x; 2.6529x over previous
//
#include <hip/hip_runtime.h>

#define LRELU_SLOPE 0.01f
#define BN_EPS 1e-5f

constexpr int B_ = 2, T_ = 8, Z_ = 16, Y_ = 32, X_ = 32;
constexpr int SP   = T_ * Z_ * Y_ * X_;   // 131072
constexpr int NPOS = B_ * SP;             // 262144
constexpr int Tp = 12, Zp = 20, Yp = 36, Xp = 36;   // padded dims (+2 each side)
constexpr int NROW = B_ * T_ * Z_ * Y_;   // 8192 x-rows
constexpr int NCB  = 512;                 // conv blocks: b2 * t8 * z16 * yh2

typedef float v4f  __attribute__((ext_vector_type(4)));
typedef __bf16 v8bf __attribute__((ext_vector_type(8)));
typedef short  v8s  __attribute__((ext_vector_type(8)));

static __device__ __forceinline__ float bf2f(short s) {
    unsigned int u = ((unsigned int)(unsigned short)s) << 16;
    float f; __builtin_memcpy(&f, &u, 4); return f;
}
static __device__ __forceinline__ short f2bf(float f) {
    unsigned int u; __builtin_memcpy(&u, &f, 4);
    u += 0x7FFF + ((u >> 16) & 1);
    return (short)(u >> 16);
}
static __device__ __forceinline__ v4f mfma16(v8bf a, v8bf b, v4f c) {
    return __builtin_amdgcn_mfma_f32_16x16x32_bf16(a, b, c, 0, 0, 0);
}

// ------------------------------------------------------------ weight repack
// W[co][ci][625] fp32 -> WB[o 626][co][ci] bf16 (o==625 = zero dummy block)
__global__ void repack_bf16(const float* __restrict__ W, short* __restrict__ WB,
                            int CO, int CI) {
    int i = blockIdx.x * 256 + threadIdx.x;
    int total = 626 * CO * CI;
    if (i >= total) return;
    int o = i / (CO * CI);
    int r = i % (CO * CI);
    int co = r / CI, ci = r % CI;
    WB[i] = (o == 625) ? (short)0 : f2bf(W[(size_t)(co * CI + ci) * 625 + o]);
}

// ------------------------------------------------------------ embed -> padded bf16 channel-last
__global__ void embed_kernel(const float* __restrict__ x, const float* __restrict__ wemb,
                             const float* __restrict__ bemb, short* __restrict__ outp) {
    int g = blockIdx.x * 256 + threadIdx.x;
    const float* xr = x + (size_t)g * 8;
    float xv[8];
#pragma unroll
    for (int f = 0; f < 8; ++f) xv[f] = xr[f];
    int xx = g & 31, yy = (g >> 5) & 31, zz = (g >> 10) & 15, tt = (g >> 14) & 7, bb = g >> 17;
    size_t addr = ((((size_t)(bb * Tp + tt + 2) * Zp + zz + 2) * Yp + yy + 2) * Xp + xx + 2) * 16;
    short ov[16];
#pragma unroll
    for (int c = 0; c < 16; ++c) {
        float a = bemb[c];
#pragma unroll
        for (int f = 0; f < 8; ++f) a = fmaf(xv[f], wemb[f * 16 + c], a);
        ov[c] = f2bf(a);
    }
    *(v8s*)(outp + addr)     = *(v8s*)ov;
    *(v8s*)(outp + addr + 8) = *(v8s*)(ov + 8);
}

// ------------------------------------------------------------ conv4d: LDS-slab row-stationary MFMA
// Block (256 thr) = (b,t,z,yh): out y in [yh*16, yh*16+16), x 0..31, all CO.
// Per (kt,kz): stage 20x36xCI input slab (contiguous global range) into LDS.
// Wave = (xh, yq): 8 out rows x 16 x. A-frags from LDS reused over valid ky x NT;
// B-frags (5 ky x NT) hoisted in registers per kx-group (global L1-resident).
template <int CI, int CO>
__global__ __launch_bounds__(256, 2) void conv_mfma(
        const short* __restrict__ inp,   // padded bf16 [b][Tp][Zp][Yp][Xp][CI]
        const short* __restrict__ wb,    // bf16 [626][CO][CI]
        const float* __restrict__ bias,
        short* __restrict__ outp,        // padded bf16 [b][Tp][Zp][Yp][Xp][CO]
        float* __restrict__ ps, float* __restrict__ psq) {
    constexpr int NT = CO / 16;
    constexpr bool PACK = (CI == 16);
    constexpr int SLAB = 20 * 36 * CI;   // shorts
    extern __shared__ short As[];
    __shared__ float lsum[32], lsq[32];

    const int tid = threadIdx.x;
    const int w = tid >> 6, lane = tid & 63;
    const int q = lane >> 4, m = lane & 15;
    const int xh = w & 1, yq = w >> 1, rb = yq * 8;
    const int blk = blockIdx.x;
    const int yh = blk & 1, z = (blk >> 1) & 15, t = (blk >> 5) & 7, b = blk >> 8;

    const int ci0 = PACK ? (q & 1) * 8 : q * 8;
    const int sel = PACK ? (q >> 1) : 0;

    v4f acc[8][NT];
#pragma unroll
    for (int al = 0; al < 8; ++al)
#pragma unroll
        for (int nt = 0; nt < NT; ++nt) acc[al][nt] = (v4f){0.f, 0.f, 0.f, 0.f};

#pragma unroll 1
    for (int kt = 0; kt < 5; ++kt) {
#pragma unroll 1
        for (int kz = 0; kz < 5; ++kz) {
            // ---- stage the (kt,kz) input slab: one contiguous global range
            const short* gA = inp +
                (((size_t)(b * Tp + t + kt) * Zp + (z + kz)) * Yp + yh * 16) * (size_t)(Xp * CI);
            for (int off = tid * 8; off < SLAB; off += 256 * 8) {
                v8s tmp = *(const v8s*)(gA + off);
                *(v8s*)(As + off) = tmp;
            }
            __syncthreads();

            if constexpr (PACK) {
#pragma unroll
                for (int kxp = 0; kxp < 3; ++kxp) {
                    const int kx0 = 2 * kxp;
                    v8bf Bf[5][NT];
#pragma unroll
                    for (int ky = 0; ky < 5; ++ky) {
                        const int o0 = (kt * 5 + kz) * 25 + ky * 5 + kx0;
                        const int od = (kxp < 2) ? 1 : (625 - o0);
                        const int oq = o0 + sel * od;
#pragma unroll
                        for (int nt = 0; nt < NT; ++nt)
                            Bf[ky][nt] = *(const v8bf*)(wb + (size_t)oq * (CO * CI) +
                                                        (nt * 16 + m) * CI + ci0);
                    }
                    const int ax = xh * 16 + m + kx0 + sel;
#pragma unroll
                    for (int rl = 0; rl < 12; ++rl) {
                        const int r = rb + rl;
                        v8bf Af = *(const v8bf*)(As + (r * 36 + ax) * CI + ci0);
#pragma unroll
                        for (int ky = 0; ky < 5; ++ky) {
                            const int al = rl - ky;
                            if (al >= 0 && al < 8) {
#pragma unroll
                                for (int nt = 0; nt < NT; ++nt)
                                    acc[al][nt] = mfma16(Af, Bf[ky][nt], acc[al][nt]);
                            }
                        }
                    }
                }
            } else {
#pragma unroll
                for (int kx = 0; kx < 5; ++kx) {
                    v8bf Bf[5][NT];
#pragma unroll
                    for (int ky = 0; ky < 5; ++ky) {
                        const int o = (kt * 5 + kz) * 25 + ky * 5 + kx;
#pragma unroll
                        for (int nt = 0; nt < NT; ++nt)
                            Bf[ky][nt] = *(const v8bf*)(wb + (size_t)o * (CO * CI) +
                                                        (nt * 16 + m) * CI + ci0);
                    }
                    const int ax = xh * 16 + m + kx;
#pragma unroll
                    for (int rl = 0; rl < 12; ++rl) {
                        const int r = rb + rl;
                        v8bf Af = *(const v8bf*)(As + (r * 36 + ax) * CI + ci0);
#pragma unroll
                        for (int ky = 0; ky < 5; ++ky) {
                            const int al = rl - ky;
                            if (al >= 0 && al < 8) {
#pragma unroll
                                for (int nt = 0; nt < NT; ++nt)
                                    acc[al][nt] = mfma16(Af, Bf[ky][nt], acc[al][nt]);
                            }
                        }
                    }
                }
            }
            __syncthreads();
        }
    }

    // ---- epilogue: bias, bf16 store to padded out, per-channel block stats
    if (tid < CO) { lsum[tid] = 0.f; lsq[tid] = 0.f; }
    __syncthreads();

    const int yg0 = yh * 16 + rb;
#pragma unroll
    for (int nt = 0; nt < NT; ++nt) {
        const int co = nt * 16 + m;
        const float bv = bias[co];
        float s = 0.f, sq = 0.f;
#pragma unroll
        for (int al = 0; al < 8; ++al) {
            const size_t orow = ((((size_t)(b * Tp + t + 2) * Zp + (z + 2)) * Yp +
                                  (yg0 + al + 2)) * Xp + (xh * 16 + 2)) * CO;
#pragma unroll
            for (int rg = 0; rg < 4; ++rg) {
                float v = acc[al][nt][rg] + bv;
                outp[orow + (size_t)(q * 4 + rg) * CO + co] = f2bf(v);
                s += v; sq += v * v;
            }
        }
        s += __shfl_down(s, 32, 64);  sq += __shfl_down(sq, 32, 64);
        s += __shfl_down(s, 16, 64);  sq += __shfl_down(sq, 16, 64);
        if (lane < 16) { atomicAdd(&lsum[co], s); atomicAdd(&lsq[co], sq); }
    }
    __syncthreads();
    if (tid < CO) {
        ps[(size_t)tid * NCB + blk]  = lsum[tid];
        psq[(size_t)tid * NCB + blk] = lsq[tid];
    }
}

// ------------------------------------------------------------ bn stats: fold into scale/shift
__global__ void stats_kernel(const float* __restrict__ ps, const float* __restrict__ psq,
                             const float* __restrict__ g, const float* __restrict__ beta,
                             float* __restrict__ scale, float* __restrict__ shift) {
    int co = blockIdx.x;
    int tid = threadIdx.x;
    float s = 0.f, q = 0.f;
    for (int i = tid; i < NCB; i += 256) {
        s += ps[(size_t)co * NCB + i];
        q += psq[(size_t)co * NCB + i];
    }
#pragma unroll
    for (int off = 32; off >= 1; off >>= 1) {
        s += __shfl_down(s, off, 64);
        q += __shfl_down(q, off, 64);
    }
    __shared__ float ss[4], qq[4];
    int w = tid >> 6, lane = tid & 63;
    if (lane == 0) { ss[w] = s; qq[w] = q; }
    __syncthreads();
    if (tid == 0) {
        float S = ss[0] + ss[1] + ss[2] + ss[3];
        float Q = qq[0] + qq[1] + qq[2] + qq[3];
        float mn = S / (float)NPOS;
        float var = Q / (float)NPOS - mn * mn;
        float rstd = rsqrtf(var + BN_EPS);
        float sc = g[co] * rstd;
        scale[co] = sc;
        shift[co] = beta[co] - mn * sc;
    }
}

// ------------------------------------------------------------ bn + leaky relu, in-place on padded bf16
template <int C>
__global__ void bn_lrelu_pad(short* __restrict__ buf, const float* __restrict__ scale,
                             const float* __restrict__ shift) {
    constexpr int GPR = 32 * C / 8;
    int gidx = blockIdx.x * 256 + threadIdx.x;
    int row = gidx / GPR;
    int gi = gidx % GPR;
    int xx = gi / (C / 8), c0 = (gi % (C / 8)) * 8;
    int y = row & 31, z = (row >> 5) & 15, t = (row >> 9) & 7, b = row >> 12;
    size_t addr = ((((size_t)(b * Tp + t + 2) * Zp + z + 2) * Yp + y + 2) * Xp + xx + 2) * C + c0;
    v8s v = *(v8s*)(buf + addr);
    short o[8];
#pragma unroll
    for (int j = 0; j < 8; ++j) {
        int c = c0 + j;
        float f = bf2f(v[j]) * scale[c] + shift[c];
        f = f > 0.f ? f : LRELU_SLOPE * f;
        o[j] = f2bf(f);
    }
    *(v8s*)(buf + addr) = *(v8s*)o;
}

// ------------------------------------------------------------ final: bn3 + lrelu + projection
__global__ void bnproj_kernel(const short* __restrict__ h, const float* __restrict__ scale,
                              const float* __restrict__ shift, const float* __restrict__ wp,
                              const float* __restrict__ bp, float* __restrict__ out) {
    int g = blockIdx.x * 256 + threadIdx.x;
    int xx = g & 31, yy = (g >> 5) & 31, zz = (g >> 10) & 15, tt = (g >> 14) & 7, bb = g >> 17;
    size_t addr = ((((size_t)(bb * Tp + tt + 2) * Zp + zz + 2) * Yp + yy + 2) * Xp + xx + 2) * 16;
    v8s lo = *(const v8s*)(h + addr);
    v8s hi = *(const v8s*)(h + addr + 8);
    float a = bp[0];
#pragma unroll
    for (int j = 0; j < 8; ++j) {
        float f = bf2f(lo[j]) * scale[j] + shift[j];
        f = f > 0.f ? f : LRELU_SLOPE * f;
        a = fmaf(f, wp[j], a);
    }
#pragma unroll
    for (int j = 0; j < 8; ++j) {
        float f = bf2f(hi[j]) * scale[8 + j] + shift[8 + j];
        f = f > 0.f ? f : LRELU_SLOPE * f;
        a = fmaf(f, wp[8 + j], a);
    }
    out[g] = a;
}

// ------------------------------------------------------------ launch
extern "C" void kernel_launch(void* const* d_in, const int* in_sizes, int n_in,
                              void* d_out, int out_size, void* d_ws, size_t ws_size,
                              hipStream_t stream) {
    const float* x    = (const float*)d_in[0];
    const float* wemb = (const float*)d_in[1];
    const float* bemb = (const float*)d_in[2];
    const float* W1   = (const float*)d_in[3];
    const float* b1   = (const float*)d_in[4];
    const float* g1   = (const float*)d_in[5];
    const float* be1  = (const float*)d_in[6];
    const float* W2   = (const float*)d_in[7];
    const float* b2   = (const float*)d_in[8];
    const float* g2   = (const float*)d_in[9];
    const float* be2  = (const float*)d_in[10];
    const float* W3   = (const float*)d_in[11];
    const float* b3   = (const float*)d_in[12];
    const float* g3   = (const float*)d_in[13];
    const float* be3  = (const float*)d_in[14];
    const float* wp   = (const float*)d_in[15];
    const float* bp   = (const float*)d_in[16];

    char* base = (char*)d_ws;
    short* P16A = (short*)(base);                  // 19,906,560 B
    short* P16B = (short*)(base + 19906560);       // 19,906,560 B
    short* P32  = (short*)(base + 39813120);       // 39,813,120 B
    short* WB1  = (short*)(base + 79626240);       // 320,512 B
    short* WB2  = (short*)(base + 79946752);       // 641,024 B
    short* WB3  = (short*)(base + 80587776);       // 641,024 B
    float* ps   = (float*)(base + 81228800);       // 262,144 B
    float* psq  = (float*)(base + 81490944);       // 262,144 B
    float* scale= (float*)(base + 81753088);       // 128 B
    float* shift= (float*)(base + 81753216);       // 128 B

    // zero the three padded activation buffers (padding must be 0 every call)
    hipMemsetAsync(base, 0, 79626240, stream);

    repack_bf16<<<(626 * 16 * 16 + 255) / 256, 256, 0, stream>>>(W1, WB1, 16, 16);
    repack_bf16<<<(626 * 32 * 16 + 255) / 256, 256, 0, stream>>>(W2, WB2, 32, 16);
    repack_bf16<<<(626 * 16 * 32 + 255) / 256, 256, 0, stream>>>(W3, WB3, 16, 32);

    embed_kernel<<<NPOS / 256, 256, 0, stream>>>(x, wemb, bemb, P16A);

    // layer 1: 16 -> 16
    conv_mfma<16, 16><<<NCB, 256, 20 * 36 * 16 * 2, stream>>>(P16A, WB1, b1, P16B, ps, psq);
    stats_kernel<<<16, 256, 0, stream>>>(ps, psq, g1, be1, scale, shift);
    bn_lrelu_pad<16><<<NROW * 64 / 256, 256, 0, stream>>>(P16B, scale, shift);

    // layer 2: 16 -> 32
    conv_mfma<16, 32><<<NCB, 256, 20 * 36 * 16 * 2, stream>>>(P16B, WB2, b2, P32, ps, psq);
    stats_kernel<<<32, 256, 0, stream>>>(ps, psq, g2, be2, scale, shift);
    bn_lrelu_pad<32><<<NROW * 128 / 256, 256, 0, stream>>>(P32, scale, shift);

    // layer 3: 32 -> 16
    conv_mfma<32, 16><<<NCB, 256, 20 * 36 * 32 * 2, stream>>>(P32, WB3, b3, P16A, ps, psq);
    stats_kernel<<<16, 256, 0, stream>>>(ps, psq, g3, be3, scale, shift);

    bnproj_kernel<<<NPOS / 256, 256, 0, stream>>>(P16A, scale, shift, wp, bp, (float*)d_out);
}

// Round 4
// 538.666 us; speedup vs baseline: 10.4177x; 1.1287x over previous
//
#include <hip/hip_runtime.h>

#define LRELU_SLOPE 0.01f
#define BN_EPS 1e-5f

constexpr int B_ = 2, T_ = 8, Z_ = 16, Y_ = 32, X_ = 32;
constexpr int SP   = T_ * Z_ * Y_ * X_;   // 131072
constexpr int NPOS = B_ * SP;             // 262144
constexpr int Tp = 12, Zp = 20, Yp = 36, Xp = 36;   // padded dims (+2 each side)
constexpr int NCB  = 256;                 // conv blocks: b2 * t8 * zp8 * yh2

typedef float v4f  __attribute__((ext_vector_type(4)));
typedef __bf16 v8bf __attribute__((ext_vector_type(8)));
typedef short  v8s  __attribute__((ext_vector_type(8)));

static __device__ __forceinline__ float bf2f(short s) {
    unsigned int u = ((unsigned int)(unsigned short)s) << 16;
    float f; __builtin_memcpy(&f, &u, 4); return f;
}
static __device__ __forceinline__ short f2bf(float f) {
    unsigned int u; __builtin_memcpy(&u, &f, 4);
    u += 0x7FFF + ((u >> 16) & 1);
    return (short)(u >> 16);
}
static __device__ __forceinline__ v4f mfma16(v8bf a, v8bf b, v4f c) {
    return __builtin_amdgcn_mfma_f32_16x16x32_bf16(a, b, c, 0, 0, 0);
}

// ------------------------------------------------------------ weight repack
// W[co][ci][625] fp32 -> WB[o 626][co][ci] bf16 (o==625 = zero dummy block)
__global__ void repack_bf16(const float* __restrict__ W, short* __restrict__ WB,
                            int CO, int CI) {
    int i = blockIdx.x * 256 + threadIdx.x;
    int total = 626 * CO * CI;
    if (i >= total) return;
    int o = i / (CO * CI);
    int r = i % (CO * CI);
    int co = r / CI, ci = r % CI;
    WB[i] = (o == 625) ? (short)0 : f2bf(W[(size_t)(co * CI + ci) * 625 + o]);
}

// ------------------------------------------------------------ embed -> padded bf16 channel-last
__global__ void embed_kernel(const float* __restrict__ x, const float* __restrict__ wemb,
                             const float* __restrict__ bemb, short* __restrict__ outp) {
    int g = blockIdx.x * 256 + threadIdx.x;
    const float* xr = x + (size_t)g * 8;
    float xv[8];
#pragma unroll
    for (int f = 0; f < 8; ++f) xv[f] = xr[f];
    int xx = g & 31, yy = (g >> 5) & 31, zz = (g >> 10) & 15, tt = (g >> 14) & 7, bb = g >> 17;
    size_t addr = ((((size_t)(bb * Tp + tt + 2) * Zp + zz + 2) * Yp + yy + 2) * Xp + xx + 2) * 16;
    short ov[16];
#pragma unroll
    for (int c = 0; c < 16; ++c) {
        float a = bemb[c];
#pragma unroll
        for (int f = 0; f < 8; ++f) a = fmaf(xv[f], wemb[f * 16 + c], a);
        ov[c] = f2bf(a);
    }
    *(v8s*)(outp + addr)     = *(v8s*)ov;
    *(v8s*)(outp + addr + 8) = *(v8s*)(ov + 8);
}

// ------------------------------------------------------------ conv4d: LDS-slab, z-pair, prefetch
// Block (512 thr, 8 waves) = (b,t,zp,yh): outputs z in {2zp, 2zp+1}, y in
// [yh*16, yh*16+16), x 0..31, all CO. 30 slabs (kt5 x zi6); per slab: prefetch
// next slab to regs, compute current from LDS, barrier, reg->LDS (+fused
// BN/lrelu/pad-mask of the INPUT layer), barrier. All-pad slabs skipped.
// Wave = (zo, xh, yq). grid swizzle: blk&7 = t  (XCD L2 locality).
template <int CI, int CO, bool BN>
__global__ __launch_bounds__(512, 2) void conv_mfma(
        const short* __restrict__ inp,   // padded bf16 [b][Tp][Zp][Yp][Xp][CI] (raw prev conv out)
        const short* __restrict__ wb,    // bf16 [626][CO][CI]
        const float* __restrict__ bias,
        const float* __restrict__ bnscale, const float* __restrict__ bnshift,
        short* __restrict__ outp,        // padded bf16 [b][Tp][Zp][Yp][Xp][CO] (raw)
        float* __restrict__ ps, float* __restrict__ psq) {
    constexpr int NT = CO / 16;
    constexpr bool PACK = (CI == 16);
    constexpr int SLAB = 20 * 36 * CI;            // shorts
    constexpr int NPF = (SLAB + 4095) / 4096;     // rounds of 512 thr x 8 shorts
    __shared__ short As[SLAB + 16];               // +16: dummy-lane read overflow (PACK)
    __shared__ float lsum[32], lsq[32];

    const int tid = threadIdx.x;
    const int w = tid >> 6, lane = tid & 63;
    const int q = lane >> 4, m = lane & 15;
    const int zo = w & 1, xh = (w >> 1) & 1, yq = w >> 2, rb = yq * 8;
    const int blk = blockIdx.x;
    const int t = blk & 7;                        // XCD swizzle: t -> XCD
    const int loc = blk >> 3;
    const int yh = loc & 1, zp = (loc >> 1) & 7, b = loc >> 4;

    const int ci0 = PACK ? (q & 1) * 8 : q * 8;
    const int sel = PACK ? (q >> 1) : 0;

    // zero the dummy tail once
    if (tid < 2) *(v8s*)(As + SLAB + tid * 8) = (v8s){0,0,0,0,0,0,0,0};

    v4f acc[8][NT];
#pragma unroll
    for (int al = 0; al < 8; ++al)
#pragma unroll
        for (int nt = 0; nt < NT; ++nt) acc[al][nt] = (v4f){0.f, 0.f, 0.f, 0.f};

    auto slab_ok = [&](int s) -> bool {
        int kt = s / 6, zi = s % 6;
        int tt = t + kt, zz = 2 * zp + zi;
        return tt >= 2 && tt < 10 && zz >= 2 && zz < 18;
    };
    v8s pf[NPF];
    auto load_pf = [&](int s) {
        int kt = s / 6, zi = s % 6;
        const short* gA = inp +
            (((size_t)(b * Tp + t + kt) * Zp + (2 * zp + zi)) * Yp + yh * 16) * (size_t)(Xp * CI);
#pragma unroll
        for (int r2 = 0; r2 < NPF; ++r2) {
            int off = tid * 8 + r2 * 4096;
            if (off < SLAB) pf[r2] = *(const v8s*)(gA + off);
        }
    };
    auto write_pf = [&]() {
#pragma unroll
        for (int r2 = 0; r2 < NPF; ++r2) {
            int off = tid * 8 + r2 * 4096;
            if (off >= SLAB) continue;
            int idx = off / CI, c0 = off % CI;
            int ypl = idx / 36, xx = idx % 36;
            int ypos = yh * 16 + ypl;
            bool pad = (ypos < 2) | (ypos >= 34) | (xx < 2) | (xx >= 34);
            short o[8];
            if (pad) {
#pragma unroll
                for (int j = 0; j < 8; ++j) o[j] = 0;
            } else if (BN) {
#pragma unroll
                for (int j = 0; j < 8; ++j) {
                    float f = bf2f(pf[r2][j]) * bnscale[c0 + j] + bnshift[c0 + j];
                    f = f > 0.f ? f : LRELU_SLOPE * f;
                    o[j] = f2bf(f);
                }
            } else {
#pragma unroll
                for (int j = 0; j < 8; ++j) o[j] = pf[r2][j];
            }
            *(v8s*)(As + off) = *(v8s*)o;
        }
    };

    if (slab_ok(0)) { load_pf(0); write_pf(); }
    __syncthreads();

#pragma unroll 1
    for (int s = 0; s < 30; ++s) {
        const bool nok = (s + 1 < 30) && slab_ok(s + 1);
        if (nok) load_pf(s + 1);

        if (slab_ok(s)) {
            const int kt = s / 6, zi = s % 6, kz = zi - zo;
            if (kz >= 0 && kz < 5) {
                const int obase = (kt * 5 + kz) * 25;
                if constexpr (PACK) {
#pragma unroll
                    for (int kxp = 0; kxp < 3; ++kxp) {
                        const int kx0 = 2 * kxp;
                        v8bf Bf[5][NT];
#pragma unroll
                        for (int ky = 0; ky < 5; ++ky) {
                            const int o0 = obase + ky * 5 + kx0;
                            const int od = (kxp < 2) ? 1 : (625 - o0);
                            const int oq = o0 + sel * od;
#pragma unroll
                            for (int nt = 0; nt < NT; ++nt)
                                Bf[ky][nt] = *(const v8bf*)(wb + (size_t)oq * (CO * CI) +
                                                            (nt * 16 + m) * CI + ci0);
                        }
                        const int ax = xh * 16 + m + kx0 + sel;
#pragma unroll
                        for (int rl = 0; rl < 12; ++rl) {
                            v8bf Af = *(const v8bf*)(As + ((rb + rl) * 36 + ax) * CI + ci0);
#pragma unroll
                            for (int ky = 0; ky < 5; ++ky) {
                                const int al = rl - ky;
                                if (al >= 0 && al < 8) {
#pragma unroll
                                    for (int nt = 0; nt < NT; ++nt)
                                        acc[al][nt] = mfma16(Af, Bf[ky][nt], acc[al][nt]);
                                }
                            }
                        }
                    }
                } else {
#pragma unroll
                    for (int kx = 0; kx < 5; ++kx) {
                        v8bf Bf[5][NT];
#pragma unroll
                        for (int ky = 0; ky < 5; ++ky) {
                            const int o = obase + ky * 5 + kx;
#pragma unroll
                            for (int nt = 0; nt < NT; ++nt)
                                Bf[ky][nt] = *(const v8bf*)(wb + (size_t)o * (CO * CI) +
                                                            (nt * 16 + m) * CI + ci0);
                        }
                        const int ax = xh * 16 + m + kx;
#pragma unroll
                        for (int rl = 0; rl < 12; ++rl) {
                            v8bf Af = *(const v8bf*)(As + ((rb + rl) * 36 + ax) * CI + ci0);
#pragma unroll
                            for (int ky = 0; ky < 5; ++ky) {
                                const int al = rl - ky;
                                if (al >= 0 && al < 8) {
#pragma unroll
                                    for (int nt = 0; nt < NT; ++nt)
                                        acc[al][nt] = mfma16(Af, Bf[ky][nt], acc[al][nt]);
                                }
                            }
                        }
                    }
                }
            }
        }
        __syncthreads();
        if (nok) write_pf();
        __syncthreads();
    }

    // ---- epilogue: bias, bf16 store (raw) to padded out, per-channel block stats
    if (tid < 32) { lsum[tid] = 0.f; lsq[tid] = 0.f; }
    __syncthreads();

    const int zout = 2 * zp + zo + 2;             // padded z
    const int yg0 = yh * 16 + rb;
#pragma unroll
    for (int nt = 0; nt < NT; ++nt) {
        const int co = nt * 16 + m;
        const float bv = bias[co];
        float s = 0.f, sq = 0.f;
#pragma unroll
        for (int al = 0; al < 8; ++al) {
            const size_t orow = ((((size_t)(b * Tp + t + 2) * Zp + zout) * Yp +
                                  (yg0 + al + 2)) * Xp + (xh * 16 + 2)) * CO;
#pragma unroll
            for (int rg = 0; rg < 4; ++rg) {
                float v = acc[al][nt][rg] + bv;
                outp[orow + (size_t)(q * 4 + rg) * CO + co] = f2bf(v);
                s += v; sq += v * v;
            }
        }
        s += __shfl_down(s, 32, 64);  sq += __shfl_down(sq, 32, 64);
        s += __shfl_down(s, 16, 64);  sq += __shfl_down(sq, 16, 64);
        if (lane < 16) { atomicAdd(&lsum[co], s); atomicAdd(&lsq[co], sq); }
    }
    __syncthreads();
    if (tid < CO) {
        ps[(size_t)tid * NCB + blk]  = lsum[tid];
        psq[(size_t)tid * NCB + blk] = lsq[tid];
    }
}

// ------------------------------------------------------------ bn stats: fold into scale/shift
__global__ void stats_kernel(const float* __restrict__ ps, const float* __restrict__ psq,
                             const float* __restrict__ g, const float* __restrict__ beta,
                             float* __restrict__ scale, float* __restrict__ shift) {
    int co = blockIdx.x;
    int tid = threadIdx.x;
    float s = 0.f, q = 0.f;
    for (int i = tid; i < NCB; i += 256) {
        s += ps[(size_t)co * NCB + i];
        q += psq[(size_t)co * NCB + i];
    }
#pragma unroll
    for (int off = 32; off >= 1; off >>= 1) {
        s += __shfl_down(s, off, 64);
        q += __shfl_down(q, off, 64);
    }
    __shared__ float ss[4], qq[4];
    int w = tid >> 6, lane = tid & 63;
    if (lane == 0) { ss[w] = s; qq[w] = q; }
    __syncthreads();
    if (tid == 0) {
        float S = ss[0] + ss[1] + ss[2] + ss[3];
        float Q = qq[0] + qq[1] + qq[2] + qq[3];
        float mn = S / (float)NPOS;
        float var = Q / (float)NPOS - mn * mn;
        float rstd = rsqrtf(var + BN_EPS);
        float sc = g[co] * rstd;
        scale[co] = sc;
        shift[co] = beta[co] - mn * sc;
    }
}

// ------------------------------------------------------------ final: bn3 + lrelu + projection
__global__ void bnproj_kernel(const short* __restrict__ h, const float* __restrict__ scale,
                              const float* __restrict__ shift, const float* __restrict__ wp,
                              const float* __restrict__ bp, float* __restrict__ out) {
    int g = blockIdx.x * 256 + threadIdx.x;
    int xx = g & 31, yy = (g >> 5) & 31, zz = (g >> 10) & 15, tt = (g >> 14) & 7, bb = g >> 17;
    size_t addr = ((((size_t)(bb * Tp + tt + 2) * Zp + zz + 2) * Yp + yy + 2) * Xp + xx + 2) * 16;
    v8s lo = *(const v8s*)(h + addr);
    v8s hi = *(const v8s*)(h + addr + 8);
    float a = bp[0];
#pragma unroll
    for (int j = 0; j < 8; ++j) {
        float f = bf2f(lo[j]) * scale[j] + shift[j];
        f = f > 0.f ? f : LRELU_SLOPE * f;
        a = fmaf(f, wp[j], a);
    }
#pragma unroll
    for (int j = 0; j < 8; ++j) {
        float f = bf2f(hi[j]) * scale[8 + j] + shift[8 + j];
        f = f > 0.f ? f : LRELU_SLOPE * f;
        a = fmaf(f, wp[8 + j], a);
    }
    out[g] = a;
}

// ------------------------------------------------------------ launch
extern "C" void kernel_launch(void* const* d_in, const int* in_sizes, int n_in,
                              void* d_out, int out_size, void* d_ws, size_t ws_size,
                              hipStream_t stream) {
    const float* x    = (const float*)d_in[0];
    const float* wemb = (const float*)d_in[1];
    const float* bemb = (const float*)d_in[2];
    const float* W1   = (const float*)d_in[3];
    const float* b1   = (const float*)d_in[4];
    const float* g1   = (const float*)d_in[5];
    const float* be1  = (const float*)d_in[6];
    const float* W2   = (const float*)d_in[7];
    const float* b2   = (const float*)d_in[8];
    const float* g2   = (const float*)d_in[9];
    const float* be2  = (const float*)d_in[10];
    const float* W3   = (const float*)d_in[11];
    const float* b3   = (const float*)d_in[12];
    const float* g3   = (const float*)d_in[13];
    const float* be3  = (const float*)d_in[14];
    const float* wp   = (const float*)d_in[15];
    const float* bp   = (const float*)d_in[16];

    char* base = (char*)d_ws;
    short* P16A = (short*)(base);                  // 19,906,560 B
    short* P16B = (short*)(base + 19906560);       // 19,906,560 B
    short* P32  = (short*)(base + 39813120);       // 39,813,120 B
    short* WB1  = (short*)(base + 79626240);       // 320,512 B
    short* WB2  = (short*)(base + 79946752);       // 641,024 B
    short* WB3  = (short*)(base + 80587776);       // 641,024 B
    float* ps   = (float*)(base + 81228800);       // 32*256*4 = 32,768 B
    float* psq  = (float*)(base + 81261568);       // 32,768 B
    float* sc1  = (float*)(base + 81294336);       // 128 B each
    float* sh1  = (float*)(base + 81294464);
    float* sc2  = (float*)(base + 81294592);
    float* sh2  = (float*)(base + 81294720);
    float* sc3  = (float*)(base + 81294848);
    float* sh3  = (float*)(base + 81294976);

    repack_bf16<<<(626 * 16 * 16 + 255) / 256, 256, 0, stream>>>(W1, WB1, 16, 16);
    repack_bf16<<<(626 * 32 * 16 + 255) / 256, 256, 0, stream>>>(W2, WB2, 32, 16);
    repack_bf16<<<(626 * 16 * 32 + 255) / 256, 256, 0, stream>>>(W3, WB3, 16, 32);

    embed_kernel<<<NPOS / 256, 256, 0, stream>>>(x, wemb, bemb, P16A);

    // layer 1: 16 -> 16 (input raw embed, no BN on stage)
    conv_mfma<16, 16, false><<<NCB, 512, 0, stream>>>(P16A, WB1, b1, nullptr, nullptr,
                                                      P16B, ps, psq);
    stats_kernel<<<16, 256, 0, stream>>>(ps, psq, g1, be1, sc1, sh1);

    // layer 2: 16 -> 32 (BN1 + lrelu fused into staging)
    conv_mfma<16, 32, true><<<NCB, 512, 0, stream>>>(P16B, WB2, b2, sc1, sh1,
                                                     P32, ps, psq);
    stats_kernel<<<32, 256, 0, stream>>>(ps, psq, g2, be2, sc2, sh2);

    // layer 3: 32 -> 16 (BN2 + lrelu fused into staging)
    conv_mfma<32, 16, true><<<NCB, 512, 0, stream>>>(P32, WB3, b3, sc2, sh2,
                                                     P16A, ps, psq);
    stats_kernel<<<16, 256, 0, stream>>>(ps, psq, g3, be3, sc3, sh3);

    // BN3 + lrelu + projection
    bnproj_kernel<<<NPOS / 256, 256, 0, stream>>>(P16A, sc3, sh3, wp, bp, (float*)d_out);
}